// Round 12
// baseline (583.669 us; speedup 1.0000x reference)
//
#include <hip/hip_runtime.h>

#define NSEG 4096
#define QSCALE 131072.0f          // 2^17 fixed-point scale
#define QINV   (1.0f / 131072.0f)
#define NB 512                    // blocks (= partial count)

typedef unsigned long long u64;
typedef unsigned int u32;
typedef float f32x4 __attribute__((ext_vector_type(4)));
typedef float f32x2 __attribute__((ext_vector_type(2)));

__device__ __forceinline__ u64 packexp(float x, float y) {
    u32 lo = __float2uint_rn(__expf(x) * QSCALE);
    u32 hi = __float2uint_rn(__expf(y) * QSCALE);
    return (u64)lo | ((u64)hi << 32);
}

// ---------------------------------------------------------------------------
// Pass 1 (R5-proven, ~170 µs: 70 stream + ~100 LDS-atomic serialization floor)
// ---------------------------------------------------------------------------
__global__ __launch_bounds__(1024) void dsp_reduce(
    const f32x4* __restrict__ xab4, const f32x4* __restrict__ xba4,
    const int2* __restrict__ src2, const int2* __restrict__ tar2,
    float* __restrict__ partials, float* __restrict__ gtab, int Eh)
{
    __shared__ u64 ls[2 * NSEG];
    for (int i = threadIdx.x; i < 2 * NSEG; i += 1024) ls[i] = 0ull;
    __syncthreads();

    const int stride = gridDim.x * 1024;
    int u = blockIdx.x * 1024 + threadIdx.x;

    f32x4 a, b; int2 s, t;
    if (u < Eh) { a = xab4[u]; b = xba4[u]; s = src2[u]; t = tar2[u]; }

    while (u < Eh) {
        int un = u + stride;
        f32x4 an, bn; int2 sn, tn;
        if (un < Eh) { an = xab4[un]; bn = xba4[un]; sn = src2[un]; tn = tar2[un]; }

        atomicAdd(&ls[s.x], packexp(a.x, a.y));
        atomicAdd(&ls[s.y], packexp(a.z, a.w));
        atomicAdd(&ls[NSEG + t.x], packexp(b.x, b.y));
        atomicAdd(&ls[NSEG + t.y], packexp(b.z, b.w));

        u = un; a = an; b = bn; s = sn; t = tn;
    }
    __syncthreads();

    if (partials) {
        f32x2* dst = (f32x2*)(partials + (size_t)blockIdx.x * (4 * NSEG));
        for (int i = threadIdx.x; i < 2 * NSEG; i += 1024) {
            u64 v = ls[i];
            f32x2 w = { (float)(u32)v * QINV, (float)(u32)(v >> 32) * QINV };
            dst[i] = w;
        }
    } else {
        for (int i = threadIdx.x; i < 2 * NSEG; i += 1024) {
            u64 v = ls[i];
            float lo = (float)(u32)v * QINV;
            float hi = (float)(u32)(v >> 32) * QINV;
            if (lo != 0.f) atomicAdd(&gtab[2 * i], lo);
            if (hi != 0.f) atomicAdd(&gtab[2 * i + 1], hi);
        }
    }
}

__global__ __launch_bounds__(256) void dsp_sum(
    const f32x4* __restrict__ partials, f32x4* __restrict__ rcp_out, int nb)
{
    int i = blockIdx.x * blockDim.x + threadIdx.x;
    f32x4 acc = {0.f, 0.f, 0.f, 0.f};
    for (int p = 0; p < nb; ++p)
        acc += __builtin_nontemporal_load(&partials[(size_t)p * NSEG + i]);
    f32x4 r;
    r.x = (acc.x > 0.f) ? 1.f / acc.x : 0.f;
    r.y = (acc.y > 0.f) ? 1.f / acc.y : 0.f;
    r.z = (acc.z > 0.f) ? 1.f / acc.z : 0.f;
    r.w = (acc.w > 0.f) ? 1.f / acc.w : 0.f;
    rcp_out[i] = r;
}

__global__ void dsp_rcp(float* __restrict__ sums, int n)
{
    int i = blockIdx.x * blockDim.x + threadIdx.x;
    if (i < n) {
        float v = sums[i];
        sums[i] = (v > 0.f) ? 1.f / v : 0.f;
    }
}

// ---------------------------------------------------------------------------
// DIAG: exact R5 norm body, REP=2 (idempotent double-write) so it lands on
// top of the profile table and finally yields norm's counters.
// ---------------------------------------------------------------------------
__global__ __launch_bounds__(1024) void dsp_norm_diag(
    const f32x4* __restrict__ xab4, const f32x4* __restrict__ xba4,
    const int2* __restrict__ src2, const int2* __restrict__ tar2,
    const f32x4* __restrict__ rcp_tab,
    f32x4* __restrict__ out, int Eh)
{
    __shared__ float ls[4 * NSEG];
    for (int i = threadIdx.x; i < NSEG; i += 1024)
        ((f32x4*)ls)[i] = rcp_tab[i];
    __syncthreads();

    const int stride = gridDim.x * 1024;
    for (int rep = 0; rep < 2; ++rep) {
        int u = blockIdx.x * 1024 + threadIdx.x;
        f32x4 a, b; int2 s, t;
        if (u < Eh) { a = xab4[u]; b = xba4[u]; s = src2[u]; t = tar2[u]; }
        while (u < Eh) {
            int un = u + stride;
            f32x4 an, bn; int2 sn, tn;
            if (un < Eh) { an = xab4[un]; bn = xba4[un]; sn = src2[un]; tn = tar2[un]; }

            f32x2 ra0 = *(const f32x2*)&ls[2 * s.x];
            f32x2 ra1 = *(const f32x2*)&ls[2 * s.y];
            f32x2 rb0 = *(const f32x2*)&ls[2 * NSEG + 2 * t.x];
            f32x2 rb1 = *(const f32x2*)&ls[2 * NSEG + 2 * t.y];

            f32x4 zab = { __expf(a.x) * ra0.x, __expf(a.y) * ra0.y,
                          __expf(a.z) * ra1.x, __expf(a.w) * ra1.y };
            f32x4 zba = { __expf(b.x) * rb0.x, __expf(b.y) * rb0.y,
                          __expf(b.z) * rb1.x, __expf(b.w) * rb1.y };
            f32x4 prod = zab * zba;

            __builtin_nontemporal_store(prod, &out[u]);
            __builtin_nontemporal_store(zab,  &out[Eh + u]);
            __builtin_nontemporal_store(zba,  &out[2 * Eh + u]);

            u = un; a = an; b = bn; s = sn; t = tn;
        }
    }
}

// ---------------------------------------------------------------------------
// EXPERIMENT: reverse-traversal norm (exact rounds). Reduce just streamed the
// inputs forward -> L3 holds the tail; reading tail-first converts ~250 MB of
// HBM reads into L3 hits (mechanism proven by R7's FETCH drop 804->410 MB).
// ---------------------------------------------------------------------------
__global__ __launch_bounds__(1024) void dsp_norm_rev(
    const f32x4* __restrict__ xab4, const f32x4* __restrict__ xba4,
    const int2* __restrict__ src2, const int2* __restrict__ tar2,
    const f32x4* __restrict__ rcp_tab,
    f32x4* __restrict__ out, int rounds, int rs, int Eh)
{
    __shared__ float ls[4 * NSEG];
    for (int i = threadIdx.x; i < NSEG; i += 1024)
        ((f32x4*)ls)[i] = rcp_tab[i];
    __syncthreads();

    const int base = blockIdx.x * 1024 + threadIdx.x;
    int u = base + (rounds - 1) * rs;

    f32x4 a = xab4[u], b = xba4[u];
    int2 s = src2[u], t = tar2[u];

    for (int r = rounds - 1; r >= 0; --r) {
        int un = u - rs;
        f32x4 an, bn; int2 sn, tn;
        if (r > 0) { an = xab4[un]; bn = xba4[un]; sn = src2[un]; tn = tar2[un]; }

        f32x2 ra0 = *(const f32x2*)&ls[2 * s.x];
        f32x2 ra1 = *(const f32x2*)&ls[2 * s.y];
        f32x2 rb0 = *(const f32x2*)&ls[2 * NSEG + 2 * t.x];
        f32x2 rb1 = *(const f32x2*)&ls[2 * NSEG + 2 * t.y];

        f32x4 zab = { __expf(a.x) * ra0.x, __expf(a.y) * ra0.y,
                      __expf(a.z) * ra1.x, __expf(a.w) * ra1.y };
        f32x4 zba = { __expf(b.x) * rb0.x, __expf(b.y) * rb0.y,
                      __expf(b.z) * rb1.x, __expf(b.w) * rb1.y };
        f32x4 prod = zab * zba;

        __builtin_nontemporal_store(prod, &out[u]);
        __builtin_nontemporal_store(zab,  &out[Eh + u]);
        __builtin_nontemporal_store(zba,  &out[2 * Eh + u]);

        u = un; a = an; b = bn; s = sn; t = tn;
    }
}

// Generic forward fallback norm (R5 verbatim).
__global__ __launch_bounds__(1024) void dsp_norm_g(
    const f32x4* __restrict__ xab4, const f32x4* __restrict__ xba4,
    const int2* __restrict__ src2, const int2* __restrict__ tar2,
    const f32x4* __restrict__ rcp_tab,
    f32x4* __restrict__ out, int Eh)
{
    __shared__ float ls[4 * NSEG];
    for (int i = threadIdx.x; i < NSEG; i += 1024)
        ((f32x4*)ls)[i] = rcp_tab[i];
    __syncthreads();

    const int stride = gridDim.x * 1024;
    int u = blockIdx.x * 1024 + threadIdx.x;
    f32x4 a, b; int2 s, t;
    if (u < Eh) { a = xab4[u]; b = xba4[u]; s = src2[u]; t = tar2[u]; }
    while (u < Eh) {
        int un = u + stride;
        f32x4 an, bn; int2 sn, tn;
        if (un < Eh) { an = xab4[un]; bn = xba4[un]; sn = src2[un]; tn = tar2[un]; }

        f32x2 ra0 = *(const f32x2*)&ls[2 * s.x];
        f32x2 ra1 = *(const f32x2*)&ls[2 * s.y];
        f32x2 rb0 = *(const f32x2*)&ls[2 * NSEG + 2 * t.x];
        f32x2 rb1 = *(const f32x2*)&ls[2 * NSEG + 2 * t.y];

        f32x4 zab = { __expf(a.x) * ra0.x, __expf(a.y) * ra0.y,
                      __expf(a.z) * ra1.x, __expf(a.w) * ra1.y };
        f32x4 zba = { __expf(b.x) * rb0.x, __expf(b.y) * rb0.y,
                      __expf(b.z) * rb1.x, __expf(b.w) * rb1.y };
        f32x4 prod = zab * zba;

        __builtin_nontemporal_store(prod, &out[u]);
        __builtin_nontemporal_store(zab,  &out[Eh + u]);
        __builtin_nontemporal_store(zba,  &out[2 * Eh + u]);

        u = un; a = an; b = bn; s = sn; t = tn;
    }
}

extern "C" void kernel_launch(void* const* d_in, const int* in_sizes, int n_in,
                              void* d_out, int out_size, void* d_ws, size_t ws_size,
                              hipStream_t stream)
{
    const int E  = in_sizes[0] / 2;
    const int Eh = E / 2;
    const f32x4* xab4 = (const f32x4*)d_in[0];
    const f32x4* xba4 = (const f32x4*)d_in[1];
    const int2*  src2 = (const int2*)d_in[2];
    const int2*  tar2 = (const int2*)d_in[3];

    float* rcp_tab  = (float*)d_ws;           // 16384 floats
    float* partials = (float*)((char*)d_ws + 65536);
    size_t need = 65536 + (size_t)NB * 65536;

    if (ws_size >= need) {
        dsp_reduce<<<NB, 1024, 0, stream>>>(xab4, xba4, src2, tar2,
                                            partials, nullptr, Eh);
        dsp_sum<<<NSEG / 256, 256, 0, stream>>>((const f32x4*)partials,
                                                (f32x4*)rcp_tab, NB);
    } else {
        (void)hipMemsetAsync(d_ws, 0, 65536, stream);
        dsp_reduce<<<NB, 1024, 0, stream>>>(xab4, xba4, src2, tar2,
                                            nullptr, rcp_tab, Eh);
        dsp_rcp<<<64, 256, 0, stream>>>(rcp_tab, 4 * NSEG);
    }

    // Diagnostic (REP=2, idempotent): exposes norm's counters in top-5.
    dsp_norm_diag<<<NB, 1024, 0, stream>>>(xab4, xba4, src2, tar2,
                                           (const f32x4*)rcp_tab,
                                           (f32x4*)d_out, Eh);

    // Experimental reverse-order norm (falls back to forward if not exact).
    const int RS = NB * 1024;
    if (Eh % RS == 0 && Eh / RS >= 1) {
        dsp_norm_rev<<<NB, 1024, 0, stream>>>(xab4, xba4, src2, tar2,
                                              (const f32x4*)rcp_tab,
                                              (f32x4*)d_out, Eh / RS, RS, Eh);
    } else {
        dsp_norm_g<<<NB, 1024, 0, stream>>>(xab4, xba4, src2, tar2,
                                            (const f32x4*)rcp_tab,
                                            (f32x4*)d_out, Eh);
    }
}

// Round 13
// 523.989 us; speedup vs baseline: 1.1139x; 1.1139x over previous
//
#include <hip/hip_runtime.h>

#define NSEG 4096
#define QSCALE 131072.0f          // 2^17 fixed-point scale
#define QINV   (1.0f / 131072.0f)
#define NB 512                    // blocks (= partial count)

typedef unsigned long long u64;
typedef unsigned int u32;
typedef float f32x4 __attribute__((ext_vector_type(4)));
typedef float f32x2 __attribute__((ext_vector_type(2)));

__device__ __forceinline__ u64 packexp(float x, float y) {
    u32 lo = __float2uint_rn(__expf(x) * QSCALE);
    u32 hi = __float2uint_rn(__expf(y) * QSCALE);
    return (u64)lo | ((u64)hi << 32);
}

// ---------------------------------------------------------------------------
// Pass 1 (split): ONE table (4096 segs) per kernel — 32 KB LDS, half the
// atomics/VALU of the combined reduce. Called twice (ab then ba). ba runs
// last: its 201 MB (x + idx) fits L3 entirely -> reverse norm reads it warm.
// R5-style 1-deep prefetch.
// ---------------------------------------------------------------------------
__global__ __launch_bounds__(1024) void dsp_reduce_h(
    const f32x4* __restrict__ x4, const int2* __restrict__ idx2,
    float* __restrict__ partials,   // [NB][8192] floats
    int Eh)
{
    __shared__ u64 ls[NSEG];        // 32 KB
    for (int i = threadIdx.x; i < NSEG; i += 1024) ls[i] = 0ull;
    __syncthreads();

    const int stride = gridDim.x * 1024;
    int u = blockIdx.x * 1024 + threadIdx.x;

    f32x4 a; int2 s;
    if (u < Eh) { a = x4[u]; s = idx2[u]; }

    while (u < Eh) {
        int un = u + stride;
        f32x4 an; int2 sn;
        if (un < Eh) { an = x4[un]; sn = idx2[un]; }

        atomicAdd(&ls[s.x], packexp(a.x, a.y));
        atomicAdd(&ls[s.y], packexp(a.z, a.w));

        u = un; a = an; s = sn;
    }
    __syncthreads();

    f32x2* dst = (f32x2*)(partials + (size_t)blockIdx.x * (2 * NSEG));
    for (int i = threadIdx.x; i < NSEG; i += 1024) {
        u64 v = ls[i];
        f32x2 w = { (float)(u32)v * QINV, (float)(u32)(v >> 32) * QINV };
        dst[i] = w;
    }
}

// ---------------------------------------------------------------------------
// Pass 2: column-sum NB partial half-tables (8192 floats each), store
// reciprocals. Called twice (ab -> rcp[0..8192), ba -> rcp[8192..16384)).
// ---------------------------------------------------------------------------
__global__ __launch_bounds__(256) void dsp_sum_h(
    const f32x4* __restrict__ partials, f32x4* __restrict__ rcp_out, int nb)
{
    int i = blockIdx.x * blockDim.x + threadIdx.x;   // 0..2047
    f32x4 acc = {0.f, 0.f, 0.f, 0.f};
    for (int p = 0; p < nb; ++p)
        acc += __builtin_nontemporal_load(&partials[(size_t)p * (NSEG / 2) + i]);
    f32x4 r;
    r.x = (acc.x > 0.f) ? 1.f / acc.x : 0.f;
    r.y = (acc.y > 0.f) ? 1.f / acc.y : 0.f;
    r.z = (acc.z > 0.f) ? 1.f / acc.z : 0.f;
    r.w = (acc.w > 0.f) ? 1.f / acc.w : 0.f;
    rcp_out[i] = r;
}

// ---------------------------------------------------------------------------
// Pass 3: reverse-traversal norm (R12-verified). Tail of xba/tar is L3-warm
// from reduce_ba. rcp tables in LDS, 1-deep prefetch, NT stores.
// LDS float layout: ab at [0,2*NSEG), ba at [2*NSEG,4*NSEG).
// ---------------------------------------------------------------------------
__global__ __launch_bounds__(1024) void dsp_norm_rev(
    const f32x4* __restrict__ xab4, const f32x4* __restrict__ xba4,
    const int2* __restrict__ src2, const int2* __restrict__ tar2,
    const f32x4* __restrict__ rcp_tab,
    f32x4* __restrict__ out, int rounds, int rs, int Eh)
{
    __shared__ float ls[4 * NSEG];
    for (int i = threadIdx.x; i < NSEG; i += 1024)
        ((f32x4*)ls)[i] = rcp_tab[i];
    __syncthreads();

    const int base = blockIdx.x * 1024 + threadIdx.x;
    int u = base + (rounds - 1) * rs;

    f32x4 a = xab4[u], b = xba4[u];
    int2 s = src2[u], t = tar2[u];

    for (int r = rounds - 1; r >= 0; --r) {
        int un = u - rs;
        f32x4 an, bn; int2 sn, tn;
        if (r > 0) { an = xab4[un]; bn = xba4[un]; sn = src2[un]; tn = tar2[un]; }

        f32x2 ra0 = *(const f32x2*)&ls[2 * s.x];
        f32x2 ra1 = *(const f32x2*)&ls[2 * s.y];
        f32x2 rb0 = *(const f32x2*)&ls[2 * NSEG + 2 * t.x];
        f32x2 rb1 = *(const f32x2*)&ls[2 * NSEG + 2 * t.y];

        f32x4 zab = { __expf(a.x) * ra0.x, __expf(a.y) * ra0.y,
                      __expf(a.z) * ra1.x, __expf(a.w) * ra1.y };
        f32x4 zba = { __expf(b.x) * rb0.x, __expf(b.y) * rb0.y,
                      __expf(b.z) * rb1.x, __expf(b.w) * rb1.y };
        f32x4 prod = zab * zba;

        __builtin_nontemporal_store(prod, &out[u]);            // zab*zba
        __builtin_nontemporal_store(zab,  &out[Eh + u]);       // zab
        __builtin_nontemporal_store(zba,  &out[2 * Eh + u]);   // zba

        u = un; a = an; b = bn; s = sn; t = tn;
    }
}

// Generic forward fallback norm (R5 verbatim).
__global__ __launch_bounds__(1024) void dsp_norm_g(
    const f32x4* __restrict__ xab4, const f32x4* __restrict__ xba4,
    const int2* __restrict__ src2, const int2* __restrict__ tar2,
    const f32x4* __restrict__ rcp_tab,
    f32x4* __restrict__ out, int Eh)
{
    __shared__ float ls[4 * NSEG];
    for (int i = threadIdx.x; i < NSEG; i += 1024)
        ((f32x4*)ls)[i] = rcp_tab[i];
    __syncthreads();

    const int stride = gridDim.x * 1024;
    int u = blockIdx.x * 1024 + threadIdx.x;
    f32x4 a, b; int2 s, t;
    if (u < Eh) { a = xab4[u]; b = xba4[u]; s = src2[u]; t = tar2[u]; }
    while (u < Eh) {
        int un = u + stride;
        f32x4 an, bn; int2 sn, tn;
        if (un < Eh) { an = xab4[un]; bn = xba4[un]; sn = src2[un]; tn = tar2[un]; }

        f32x2 ra0 = *(const f32x2*)&ls[2 * s.x];
        f32x2 ra1 = *(const f32x2*)&ls[2 * s.y];
        f32x2 rb0 = *(const f32x2*)&ls[2 * NSEG + 2 * t.x];
        f32x2 rb1 = *(const f32x2*)&ls[2 * NSEG + 2 * t.y];

        f32x4 zab = { __expf(a.x) * ra0.x, __expf(a.y) * ra0.y,
                      __expf(a.z) * ra1.x, __expf(a.w) * ra1.y };
        f32x4 zba = { __expf(b.x) * rb0.x, __expf(b.y) * rb0.y,
                      __expf(b.z) * rb1.x, __expf(b.w) * rb1.y };
        f32x4 prod = zab * zba;

        __builtin_nontemporal_store(prod, &out[u]);
        __builtin_nontemporal_store(zab,  &out[Eh + u]);
        __builtin_nontemporal_store(zba,  &out[2 * Eh + u]);

        u = un; a = an; b = bn; s = sn; t = tn;
    }
}

extern "C" void kernel_launch(void* const* d_in, const int* in_sizes, int n_in,
                              void* d_out, int out_size, void* d_ws, size_t ws_size,
                              hipStream_t stream)
{
    const int E  = in_sizes[0] / 2;
    const int Eh = E / 2;
    const f32x4* xab4 = (const f32x4*)d_in[0];
    const f32x4* xba4 = (const f32x4*)d_in[1];
    const int2*  src2 = (const int2*)d_in[2];
    const int2*  tar2 = (const int2*)d_in[3];

    // ws: rcp f32[16384] (64KB) | partials_ab NB*32KB (16MB) | partials_ba (16MB)
    float* rcp_tab  = (float*)d_ws;
    float* part_ab  = (float*)((char*)d_ws + 65536);
    float* part_ba  = part_ab + (size_t)NB * (2 * NSEG);
    size_t need = 65536 + (size_t)NB * 65536;

    if (ws_size >= need) {
        // ab first; ba LAST so xba+tar (201 MB, fits L3) stay warm for norm.
        dsp_reduce_h<<<NB, 1024, 0, stream>>>(xab4, src2, part_ab, Eh);
        dsp_reduce_h<<<NB, 1024, 0, stream>>>(xba4, tar2, part_ba, Eh);
        dsp_sum_h<<<(NSEG / 2) / 256, 256, 0, stream>>>(
            (const f32x4*)part_ab, (f32x4*)rcp_tab, NB);
        dsp_sum_h<<<(NSEG / 2) / 256, 256, 0, stream>>>(
            (const f32x4*)part_ba, (f32x4*)(rcp_tab + 2 * NSEG), NB);
    }

    const int RS = NB * 1024;
    if (ws_size >= need && Eh % RS == 0 && Eh / RS >= 1) {
        dsp_norm_rev<<<NB, 1024, 0, stream>>>(xab4, xba4, src2, tar2,
                                              (const f32x4*)rcp_tab,
                                              (f32x4*)d_out, Eh / RS, RS, Eh);
    } else {
        dsp_norm_g<<<NB, 1024, 0, stream>>>(xab4, xba4, src2, tar2,
                                            (const f32x4*)rcp_tab,
                                            (f32x4*)d_out, Eh);
    }
}